// Round 2
// baseline (6680.059 us; speedup 1.0000x reference)
//
#include <hip/hip_runtime.h>
#include <hip/hip_bf16.h>
#include <math.h>

#define N_PTS 131072
#define NSEG  8192
#define HD    128
#define NKK   20
#define PRED  12
#define KTOT  170   // 2 (rel) + 40 (dtp) + 128 (h)

typedef __hip_bfloat16 bf16;

__device__ __forceinline__ float b2f(bf16 x){ return __bfloat162float(x); }
__device__ __forceinline__ float sigm(float x){ return 1.0f/(1.0f+__expf(-x)); }
__device__ __forceinline__ float tanh_f(float x){
  x = fminf(15.f, fmaxf(-15.f, x));
  float e = __expf(2.f*x);
  return (e-1.f)/(e+1.f);
}
// flag-predicated float load: bf ? bf16 : fp32
__device__ __forceinline__ float ldf(const void* p, long long i, bool bf){
  return bf ? __bfloat162float(((const bf16*)p)[i]) : ((const float*)p)[i];
}
__device__ __forceinline__ int ldseg(const void* p, long long i, bool i64){
  return i64 ? (int)(((const long long*)p)[i]) : ((const int*)p)[i];
}
__device__ __forceinline__ void stf(void* p, long long i, float v, bool bf){
  if(bf) ((bf16*)p)[i] = __float2bfloat16(v);
  else   ((float*)p)[i] = v;
}

// ---------- dtype probes: flags[0]=float-is-bf16, flags[1]=segids-int64, flags[2]=mask mode(0=i32,1=byte,2=i64)
__global__ void k_probe(const unsigned short* __restrict__ wx,
                        const int* __restrict__ seg,
                        const unsigned char* __restrict__ msk,
                        int* __restrict__ flags){
  int lane = threadIdx.x & 63;
  unsigned short h1 = wx[2*lane], h2 = wx[128+2*lane];
  int e1 = (h1>>7)&255, e2 = (h2>>7)&255;
  bool p1 = (e1>=100 && e1<=132), p2 = (e2>=100 && e2<=132);
  int cnt = __popcll(__ballot(p1)) + __popcll(__ballot(p2));
  int v = seg[65536+lane];
  int zc = __popcll(__ballot((lane&1) && v==0));
  bool nz1=false, nz2=false;
  for(int i=lane;i<4096;i+=64){
    unsigned char b = msk[i];
    if((i&3)!=0 && b) nz1=true;
    if((i&7)==4 && b) nz2=true;
  }
  unsigned long long b1 = __ballot(nz1), b2 = __ballot(nz2);
  if(lane==0){
    flags[0] = (cnt>=64) ? 1 : 0;
    flags[1] = (zc>=24) ? 1 : 0;
    flags[2] = b1 ? 1 : (b2 ? 0 : 2);
  }
}

__global__ void k_conv(const unsigned char* __restrict__ mraw, const int* __restrict__ flags,
                       unsigned char* __restrict__ mask){
  int i = blockIdx.x*256+threadIdx.x;
  if(i>=N_PTS) return;
  int mode = flags[2];
  unsigned char v;
  if(mode==1)      v = mraw[i]!=0;
  else if(mode==0) v = ((const int*)mraw)[i]!=0;
  else             v = ((const long long*)mraw)[i]!=0;
  mask[i]=v;
}

__global__ void k_segstart(const void* __restrict__ seg, const int* __restrict__ flags,
                           int* __restrict__ start){
  int s = blockIdx.x*256+threadIdx.x;
  if(s>NSEG) return;
  bool i64 = flags[1]!=0;
  int lo=0, hi=N_PTS;
  while(lo<hi){ int mid=(lo+hi)>>1; if(ldseg(seg,mid,i64)<s) lo=mid+1; else hi=mid; }
  start[s]=lo;
}

// ---------- fold weights: Wcat (176x512 fp32) rows: [W_pos@Wx0 ; W_fld@Wx1 ; Wh ; 0pad], bias_eff ----------
__global__ void k_fold(const void* __restrict__ Wpos, const void* __restrict__ bpos,
                       const void* __restrict__ Wfld, const void* __restrict__ bfld,
                       const void* __restrict__ Wx,   const void* __restrict__ Wh,
                       const void* __restrict__ blstm, const int* __restrict__ flags,
                       float* __restrict__ wcat, float* __restrict__ bias){
  int idx = blockIdx.x*256+threadIdx.x;
  if(idx >= 177*512) return;
  bool bf = flags[0]!=0;
  int r = idx>>9, c = idx&511;
  if(r<2){
    float a=0; for(int j=0;j<64;j++) a += ldf(Wpos,r*64+j,bf)*ldf(Wx,j*512+c,bf);
    wcat[r*512+c]=a;
  } else if(r<42){
    int rr=r-2; float a=0; for(int j=0;j<64;j++) a += ldf(Wfld,rr*64+j,bf)*ldf(Wx,(64+j)*512+c,bf);
    wcat[r*512+c]=a;
  } else if(r<170){
    wcat[r*512+c]=ldf(Wh,(r-42)*512+c,bf);
  } else if(r<176){
    wcat[r*512+c]=0.f;
  } else {
    float a=ldf(blstm,c,bf);
    for(int j=0;j<64;j++) a += ldf(bpos,j,bf)*ldf(Wx,j*512+c,bf) + ldf(bfld,j,bf)*ldf(Wx,(64+j)*512+c,bf);
    bias[c]=a;
  }
}

// ---------- init ----------
__global__ void k_init(const void* __restrict__ sf, const void* __restrict__ lastpos,
                       const void* __restrict__ alpha0, const void* __restrict__ fd0,
                       const void* __restrict__ Wout, const void* __restrict__ bout,
                       const int* __restrict__ flags,
                       float* __restrict__ h, float* __restrict__ c,
                       float* __restrict__ rel, float* __restrict__ pos,
                       float* __restrict__ fd, float* __restrict__ al,
                       void* __restrict__ traj){
  int grp = threadIdx.x>>6, lane = threadIdx.x&63;
  int p = blockIdx.x*4+grp;
  bool bf = flags[0]!=0;
  float h0 = ldf(sf,(long long)p*128+lane,bf);
  float h1 = ldf(sf,(long long)p*128+64+lane,bf);
  h[p*128+lane]=h0; h[p*128+64+lane]=h1;
  c[p*128+lane]=0.f; c[p*128+64+lane]=0.f;
  float o0 = h0*ldf(Wout,lane*2,bf)   + h1*ldf(Wout,(64+lane)*2,bf);
  float o1 = h0*ldf(Wout,lane*2+1,bf) + h1*ldf(Wout,(64+lane)*2+1,bf);
  for(int m=1;m<64;m<<=1){ o0 += __shfl_xor(o0,m); o1 += __shfl_xor(o1,m); }
  o0 += ldf(bout,0,bf); o1 += ldf(bout,1,bf);
  float a = 0.f;
  if(lane<NKK) a = ldf(alpha0,(long long)p*NKK+lane,bf);
  float s = a;
  for(int m=1;m<64;m<<=1) s += __shfl_xor(s,m);
  if(lane<NKK) al[p*NKK+lane] = a/s;
  if(lane<2*NKK) fd[p*2*NKK+lane] = ldf(fd0,(long long)p*2*NKK+lane,bf);
  if(lane==0){
    rel[p*2]=o0; rel[p*2+1]=o1;
    pos[p*2]   = ldf(lastpos,p*2,bf)  +o0;
    pos[p*2+1] = ldf(lastpos,p*2+1,bf)+o1;
    stf(traj, (long long)p*2,   o0, bf);
    stf(traj, (long long)p*2+1, o1, bf);
  }
}

// ---------- per-step: segment max over h ----------
__global__ void s1a_segmax(const float* __restrict__ h, const int* __restrict__ start,
                           float* __restrict__ segmax){
  int s = blockIdx.x;
  int d = threadIdx.x;
  int a = start[s], b = start[s+1];
  float m = -INFINITY;
  for(int i=a;i<b;i++) m = fmaxf(m, h[i*128+d]);
  if(a>=b) m = 0.f;
  segmax[s*128+d]=m;
}

// ---------- per-step: pool = relu(segmax @ W_pool + b_pool) ----------
__global__ void s1b_pool(const float* __restrict__ segmax, const void* __restrict__ Wpool,
                         const void* __restrict__ bpool, const int* __restrict__ flags,
                         float* __restrict__ pool){
  int s = blockIdx.x*2 + (threadIdx.x>>7);
  int cc = threadIdx.x&127;
  bool bf = flags[0]!=0;
  const float* sm = segmax + s*128;
  float acc = ldf(bpool,cc,bf);
  for(int k=0;k<128;k++) acc += sm[k]*ldf(Wpool,k*128+cc,bf);
  pool[s*128+cc] = fmaxf(acc, 0.f);
}

// ---------- per-step: contrib = pool @ Wx[128:256,:] ----------
__global__ void s1c_contrib(const float* __restrict__ pool, const void* __restrict__ Wx,
                            const int* __restrict__ flags, float* __restrict__ contrib){
  int s = blockIdx.x>>1;
  int cc = ((blockIdx.x&1)<<8) + threadIdx.x;
  bool bf = flags[0]!=0;
  const float* pl = pool + s*128;
  float acc=0.f;
  for(int k=0;k<128;k++) acc += pl[k]*ldf(Wx,(128+k)*512+cc,bf);
  contrib[s*512+cc]=acc;
}

// ---------- per-step: gates GEMM (M=64 x N=512 x K=170) + fused LSTM ----------
__launch_bounds__(512,4)
__global__ void s2_gemm_lstm(const float* __restrict__ rel, const float* __restrict__ fd,
                             const float* __restrict__ al,  float* __restrict__ h_st,
                             float* __restrict__ c_st,
                             const float* __restrict__ wcat, const float* __restrict__ bias,
                             const float* __restrict__ contrib,
                             const void* __restrict__ segids, const int* __restrict__ flags,
                             const unsigned char* __restrict__ mask){
  __shared__ float W_lds[32*512];
  __shared__ float A_lds[64*33];
  const int tid = threadIdx.x;
  const int P0  = blockIdx.x*64;
  const int pb  = (tid&7)*8;
  const int d0  = (tid>>3)*2;
  const bool i64 = flags[1]!=0;

  float acc[8][8];
  #pragma unroll
  for(int i=0;i<8;i++)
    #pragma unroll
    for(int j=0;j<8;j++) acc[i][j]=0.f;

  const int sp = tid>>3;
  const int sk = (tid&7)*4;

  for(int k0=0;k0<KTOT;k0+=32){
    const int kw = min(32, KTOT-k0);
    #pragma unroll
    for(int j=0;j<4;j++){
      int ksub = sk+j;
      if(ksub<kw){
        int k = k0+ksub;
        int P = P0+sp;
        float v;
        if(k<2)        v = rel[P*2+k];
        else if(k<42){ int kk=k-2; v = fd[P*40+kk]*al[P*20+(kk>>1)]; }
        else           v = h_st[P*128+(k-42)];
        A_lds[sp*33+ksub] = v;
      }
    }
    for(int m=0;m<kw;m++){
      W_lds[m*512+tid] = wcat[(k0+m)*512+tid];
    }
    __syncthreads();
    #pragma unroll 4
    for(int k=0;k<kw;k++){
      const float2* wrow = (const float2*)&W_lds[k*512];
      float2 wv0 = wrow[0*64 + (d0>>1)];
      float2 wv1 = wrow[1*64 + (d0>>1)];
      float2 wv2 = wrow[2*64 + (d0>>1)];
      float2 wv3 = wrow[3*64 + (d0>>1)];
      #pragma unroll
      for(int i=0;i<8;i++){
        float a = A_lds[(pb+i)*33+k];
        acc[i][0] += a*wv0.x; acc[i][1] += a*wv0.y;
        acc[i][2] += a*wv1.x; acc[i][3] += a*wv1.y;
        acc[i][4] += a*wv2.x; acc[i][5] += a*wv2.y;
        acc[i][6] += a*wv3.x; acc[i][7] += a*wv3.y;
      }
    }
    __syncthreads();
  }

  float2 bi0 = *(const float2*)(bias + 0*128 + d0);
  float2 bi1 = *(const float2*)(bias + 1*128 + d0);
  float2 bi2 = *(const float2*)(bias + 2*128 + d0);
  float2 bi3 = *(const float2*)(bias + 3*128 + d0);
  #pragma unroll
  for(int i=0;i<8;i++){
    int P = P0+pb+i;
    int sg = ldseg(segids,P,i64);
    bool msk = mask[P]!=0;
    const float* cb = contrib + (size_t)sg*512;
    float gix = acc[i][0] + bi0.x + cb[0*128+d0];
    float giy = acc[i][1] + bi0.y + cb[0*128+d0+1];
    float gfx = acc[i][2] + bi1.x + cb[1*128+d0];
    float gfy = acc[i][3] + bi1.y + cb[1*128+d0+1];
    float ggx = acc[i][4] + bi2.x + cb[2*128+d0];
    float ggy = acc[i][5] + bi2.y + cb[2*128+d0+1];
    float gox = acc[i][6] + bi3.x + cb[3*128+d0];
    float goy = acc[i][7] + bi3.y + cb[3*128+d0+1];
    float2 cold = *(const float2*)(c_st + (size_t)P*128 + d0);
    float2 hold = *(const float2*)(h_st + (size_t)P*128 + d0);
    float cnx = sigm(gfx)*cold.x + sigm(gix)*tanh_f(ggx);
    float cny = sigm(gfy)*cold.y + sigm(giy)*tanh_f(ggy);
    float hnx = sigm(gox)*tanh_f(cnx);
    float hny = sigm(goy)*tanh_f(cny);
    if(!msk){ cnx=cold.x; cny=cold.y; hnx=hold.x; hny=hold.y; }
    float2 cw; cw.x=cnx; cw.y=cny;
    float2 hw; hw.x=hnx; hw.y=hny;
    *(float2*)(c_st + (size_t)P*128 + d0) = cw;
    *(float2*)(h_st + (size_t)P*128 + d0) = hw;
  }
}

// ---------- per-step epilogue; writes traj at step t with dtype-correct stride ----------
__global__ void s3_post(const float* __restrict__ h2, float* __restrict__ rel,
                        float* __restrict__ pos, float* __restrict__ fd, float* __restrict__ al,
                        const void* __restrict__ Wout, const void* __restrict__ bout,
                        const void* __restrict__ fieldA, const void* __restrict__ trans,
                        const int* __restrict__ flags,
                        const unsigned char* __restrict__ mask, void* __restrict__ traj, int t){
  int grp = threadIdx.x>>6, lane = threadIdx.x&63;
  int p = blockIdx.x*4+grp;
  bool bf = flags[0]!=0;
  float h0 = h2[p*128+lane], h1 = h2[p*128+64+lane];
  float o0 = h0*ldf(Wout,lane*2,bf)   + h1*ldf(Wout,(64+lane)*2,bf);
  float o1 = h0*ldf(Wout,lane*2+1,bf) + h1*ldf(Wout,(64+lane)*2+1,bf);
  for(int m=1;m<64;m<<=1){ o0 += __shfl_xor(o0,m); o1 += __shfl_xor(o1,m); }
  o0 += ldf(bout,0,bf); o1 += ldf(bout,1,bf);
  bool msk = mask[p]!=0;
  float r0 = rel[p*2], r1 = rel[p*2+1];
  if(msk){ r0=o0; r1=o1; }
  float pn0 = pos[p*2]+r0, pn1 = pos[p*2+1]+r1;
  float ad = -INFINITY;
  if(lane<NKK){
    float a2=0.f;
    for(int i=0;i<NKK;i++) a2 += al[p*NKK+i]*ldf(trans,i*NKK+lane,bf);
    ad = a2;
  }
  float mx = ad;
  for(int m=1;m<64;m<<=1) mx = fmaxf(mx, __shfl_xor(mx,m));
  float e = (lane<NKK)? __expf(ad-mx) : 0.f;
  float se = e;
  for(int m=1;m<64;m<<=1) se += __shfl_xor(se,m);
  if(msk && lane<NKK) al[p*NKK+lane] = e/se;
  if(msk && lane<2*NKK){
    int kk=lane>>1, ee=lane&1;
    float fp = pn0*ldf(fieldA,kk*4+ee,bf) + pn1*ldf(fieldA,kk*4+2+ee,bf);
    fd[p*2*NKK+lane]=fp;
  }
  if(lane==0){
    rel[p*2]=r0; rel[p*2+1]=r1;
    pos[p*2]=pn0; pos[p*2+1]=pn1;
    long long base = (long long)t*N_PTS*2 + (long long)p*2;
    stf(traj, base,   r0, bf);
    stf(traj, base+1, r1, bf);
  }
}

extern "C" void kernel_launch(void* const* d_in, const int* in_sizes, int n_in,
                              void* d_out, int out_size, void* d_ws, size_t ws_size,
                              hipStream_t stream){
  const void* sf      = d_in[0];
  const void* lastpos = d_in[1];
  const void* alpha0  = d_in[2];
  const void* fd0     = d_in[3];
  const void* Wpos    = d_in[4];
  const void* bpos    = d_in[5];
  const void* Wfld    = d_in[6];
  const void* bfld    = d_in[7];
  const void* Wpool   = d_in[8];
  const void* bpool   = d_in[9];
  const void* Wx      = d_in[10];
  const void* Wh      = d_in[11];
  const void* blstm   = d_in[12];
  const void* Wout    = d_in[13];
  const void* bout    = d_in[14];
  const void* fieldA  = d_in[15];
  const void* trans   = d_in[16];
  const void* segids  = d_in[17];
  const unsigned char* maskraw = (const unsigned char*)d_in[18];

  char* ws = (char*)d_ws;
  size_t o = 0;
  auto alc = [&](size_t b){ size_t r=o; o=(o+b+255)&~(size_t)255; return r; };
  float* h_st    = (float*)(ws+alc((size_t)N_PTS*128*4));
  float* c_st    = (float*)(ws+alc((size_t)N_PTS*128*4));
  float* rel     = (float*)(ws+alc((size_t)N_PTS*2*4));
  float* pos     = (float*)(ws+alc((size_t)N_PTS*2*4));
  float* fd      = (float*)(ws+alc((size_t)N_PTS*40*4));
  float* al      = (float*)(ws+alc((size_t)N_PTS*20*4));
  int*   segst   = (int*)  (ws+alc((size_t)(NSEG+1)*4));
  float* segmax  = (float*)(ws+alc((size_t)NSEG*128*4));
  float* pool    = (float*)(ws+alc((size_t)NSEG*128*4));
  float* contrib = (float*)(ws+alc((size_t)NSEG*512*4));
  float* wcat    = (float*)(ws+alc((size_t)176*512*4));
  float* bias    = (float*)(ws+alc((size_t)512*4));
  unsigned char* mask = (unsigned char*)(ws+alc((size_t)N_PTS));
  int*   flags   = (int*)  (ws+alc(64));

  k_probe<<<1,64,0,stream>>>((const unsigned short*)Wx, (const int*)segids, maskraw, flags);
  k_conv<<<512,256,0,stream>>>(maskraw, flags, mask);
  k_segstart<<<33,256,0,stream>>>(segids, flags, segst);
  k_fold<<<354,256,0,stream>>>(Wpos,bpos,Wfld,bfld,Wx,Wh,blstm,flags,wcat,bias);
  k_init<<<32768,256,0,stream>>>(sf,lastpos,alpha0,fd0,Wout,bout,flags,h_st,c_st,rel,pos,fd,al,d_out);

  for(int t=1;t<PRED;t++){
    s1a_segmax<<<NSEG,128,0,stream>>>(h_st, segst, segmax);
    s1b_pool<<<NSEG/2,256,0,stream>>>(segmax, Wpool, bpool, flags, pool);
    s1c_contrib<<<NSEG*2,256,0,stream>>>(pool, Wx, flags, contrib);
    s2_gemm_lstm<<<N_PTS/64,512,0,stream>>>(rel, fd, al, h_st, c_st, wcat, bias, contrib, segids, flags, mask);
    s3_post<<<N_PTS/4,256,0,stream>>>(h_st, rel, pos, fd, al, Wout, bout, fieldA, trans, flags, mask, d_out, t);
  }
}

// Round 3
// 4110.707 us; speedup vs baseline: 1.6250x; 1.6250x over previous
//
#include <hip/hip_runtime.h>
#include <hip/hip_bf16.h>
#include <math.h>

#define N_PTS 131072
#define NSEG  8192
#define NKK   20
#define PRED  12
#define KP    192   // padded K: 2 rel + 40 dtp + 128 h + 22 zero

typedef __hip_bfloat16 bf16;
typedef __attribute__((ext_vector_type(8))) short short8;
typedef __attribute__((ext_vector_type(4))) float float4v;

__device__ __forceinline__ float b2f(bf16 x){ return __bfloat162float(x); }
__device__ __forceinline__ float sigm(float x){ return 1.0f/(1.0f+__expf(-x)); }
__device__ __forceinline__ float tanh_f(float x){
  x = fminf(15.f, fmaxf(-15.f, x));
  float e = __expf(2.f*x);
  return (e-1.f)/(e+1.f);
}
__device__ __forceinline__ float ldf(const void* p, long long i, bool bf){
  return bf ? __bfloat162float(((const bf16*)p)[i]) : ((const float*)p)[i];
}
__device__ __forceinline__ int ldseg(const void* p, long long i, bool i64){
  return i64 ? (int)(((const long long*)p)[i]) : ((const int*)p)[i];
}
__device__ __forceinline__ void stf(void* p, long long i, float v, bool bf){
  if(bf) ((bf16*)p)[i] = __float2bfloat16(v);
  else   ((float*)p)[i] = v;
}

// ---------- dtype probes: flags[0]=float-is-bf16, flags[1]=segids-int64, flags[2]=mask mode(0=i32,1=byte,2=i64)
__global__ void k_probe(const unsigned short* __restrict__ wx,
                        const int* __restrict__ seg,
                        const unsigned char* __restrict__ msk,
                        int* __restrict__ flags){
  int lane = threadIdx.x & 63;
  unsigned short h1 = wx[2*lane], h2 = wx[128+2*lane];
  int e1 = (h1>>7)&255, e2 = (h2>>7)&255;
  bool p1 = (e1>=100 && e1<=132), p2 = (e2>=100 && e2<=132);
  int cnt = __popcll(__ballot(p1)) + __popcll(__ballot(p2));
  int v = seg[65536+lane];
  int zc = __popcll(__ballot((lane&1) && v==0));
  bool nz1=false, nz2=false;
  for(int i=lane;i<4096;i+=64){
    unsigned char b = msk[i];
    if((i&3)!=0 && b) nz1=true;
    if((i&7)==4 && b) nz2=true;
  }
  unsigned long long b1 = __ballot(nz1), b2 = __ballot(nz2);
  if(lane==0){
    flags[0] = (cnt>=64) ? 1 : 0;
    flags[1] = (zc>=24) ? 1 : 0;
    flags[2] = b1 ? 1 : (b2 ? 0 : 2);
  }
}

__global__ void k_conv(const unsigned char* __restrict__ mraw, const int* __restrict__ flags,
                       unsigned char* __restrict__ mask){
  int i = blockIdx.x*256+threadIdx.x;
  if(i>=N_PTS) return;
  int mode = flags[2];
  unsigned char v;
  if(mode==1)      v = mraw[i]!=0;
  else if(mode==0) v = ((const int*)mraw)[i]!=0;
  else             v = ((const long long*)mraw)[i]!=0;
  mask[i]=v;
}

__global__ void k_segstart(const void* __restrict__ seg, const int* __restrict__ flags,
                           int* __restrict__ start){
  int s = blockIdx.x*256+threadIdx.x;
  if(s>NSEG) return;
  bool i64 = flags[1]!=0;
  int lo=0, hi=N_PTS;
  while(lo<hi){ int mid=(lo+hi)>>1; if(ldseg(seg,mid,i64)<s) lo=mid+1; else hi=mid; }
  start[s]=lo;
}

// ---------- fold weights into wT[512][192] bf16 (n-major, k-contiguous, B-operand layout) + bias_eff fp32[512]
__global__ void k_fold(const void* __restrict__ Wpos, const void* __restrict__ bpos,
                       const void* __restrict__ Wfld, const void* __restrict__ bfld,
                       const void* __restrict__ Wx,   const void* __restrict__ Wh,
                       const void* __restrict__ blstm, const int* __restrict__ flags,
                       short* __restrict__ wT, float* __restrict__ bias){
  int idx = blockIdx.x*256+threadIdx.x;
  bool bf = flags[0]!=0;
  if(idx < 512*KP){
    int n = idx/KP, k = idx - n*KP;
    float v;
    if(k<2){
      float a=0; for(int j=0;j<64;j++) a += ldf(Wpos,k*64+j,bf)*ldf(Wx,j*512+n,bf);
      v=a;
    } else if(k<42){
      int kk=k-2; float a=0; for(int j=0;j<64;j++) a += ldf(Wfld,kk*64+j,bf)*ldf(Wx,(64+j)*512+n,bf);
      v=a;
    } else if(k<170){
      v = ldf(Wh,(long long)(k-42)*512+n,bf);
    } else v = 0.f;
    ((bf16*)wT)[(long long)n*KP+k] = __float2bfloat16(v);
  } else if(idx < 512*KP+512){
    int c = idx - 512*KP;
    float a=ldf(blstm,c,bf);
    for(int j=0;j<64;j++) a += ldf(bpos,j,bf)*ldf(Wx,j*512+c,bf) + ldf(bfld,j,bf)*ldf(Wx,(64+j)*512+c,bf);
    bias[c]=a;
  }
}

// ---------- init: build Apk[p][192], c=0, rel/pos fp32, al fp32, traj[0] ----------
__global__ void k_init(const void* __restrict__ sf, const void* __restrict__ lastpos,
                       const void* __restrict__ alpha0, const void* __restrict__ fd0,
                       const void* __restrict__ Wout, const void* __restrict__ bout,
                       const int* __restrict__ flags,
                       short* __restrict__ Apk, float* __restrict__ c,
                       float* __restrict__ rel, float* __restrict__ pos,
                       float* __restrict__ al, void* __restrict__ traj){
  int grp = threadIdx.x>>6, lane = threadIdx.x&63;
  int p = blockIdx.x*4+grp;
  bool bf = flags[0]!=0;
  bf16* Ap = (bf16*)Apk + (long long)p*KP;
  float h0 = ldf(sf,(long long)p*128+lane,bf);
  float h1 = ldf(sf,(long long)p*128+64+lane,bf);
  Ap[42+lane]      = __float2bfloat16(h0);
  Ap[42+64+lane]   = __float2bfloat16(h1);
  c[(long long)p*128+lane]=0.f; c[(long long)p*128+64+lane]=0.f;
  float o0 = h0*ldf(Wout,lane*2,bf)   + h1*ldf(Wout,(64+lane)*2,bf);
  float o1 = h0*ldf(Wout,lane*2+1,bf) + h1*ldf(Wout,(64+lane)*2+1,bf);
  for(int m=1;m<64;m<<=1){ o0 += __shfl_xor(o0,m); o1 += __shfl_xor(o1,m); }
  o0 += ldf(bout,0,bf); o1 += ldf(bout,1,bf);
  float a = 0.f;
  if(lane<NKK) a = ldf(alpha0,(long long)p*NKK+lane,bf);
  float s = a;
  for(int m=1;m<64;m<<=1) s += __shfl_xor(s,m);
  float aln = a/s;
  if(lane<NKK) al[(long long)p*NKK+lane] = aln;
  float alq = __shfl(aln, lane>>1);
  if(lane<2*NKK) Ap[2+lane] = __float2bfloat16(ldf(fd0,(long long)p*2*NKK+lane,bf)*alq);
  if(lane<22)    Ap[170+lane] = __float2bfloat16(0.f);
  if(lane==0){
    Ap[0]=__float2bfloat16(o0); Ap[1]=__float2bfloat16(o1);
    rel[p*2]=o0; rel[p*2+1]=o1;
    pos[p*2]   = ldf(lastpos,p*2,bf)  +o0;
    pos[p*2+1] = ldf(lastpos,p*2+1,bf)+o1;
    stf(traj, (long long)p*2,   o0, bf);
    stf(traj, (long long)p*2+1, o1, bf);
  }
}

// ---------- per-step: segment max over h (bf16 in Apk) ----------
__global__ void s1a_segmax(const short* __restrict__ Apk, const int* __restrict__ start,
                           float* __restrict__ segmax){
  int s = blockIdx.x;
  int d = threadIdx.x;
  int a = start[s], b = start[s+1];
  float m = -INFINITY;
  for(int i=a;i<b;i++) m = fmaxf(m, b2f(((const bf16*)Apk)[(long long)i*KP+42+d]));
  if(a>=b) m = 0.f;
  segmax[s*128+d]=m;
}

// ---------- per-step: pool = relu(segmax @ W_pool + b_pool) ----------
__global__ void s1b_pool(const float* __restrict__ segmax, const void* __restrict__ Wpool,
                         const void* __restrict__ bpool, const int* __restrict__ flags,
                         float* __restrict__ pool){
  int s = blockIdx.x*2 + (threadIdx.x>>7);
  int cc = threadIdx.x&127;
  bool bf = flags[0]!=0;
  const float* sm = segmax + s*128;
  float acc = ldf(bpool,cc,bf);
  for(int k=0;k<128;k++) acc += sm[k]*ldf(Wpool,k*128+cc,bf);
  pool[s*128+cc] = fmaxf(acc, 0.f);
}

// ---------- per-step: contrib = pool @ Wx[128:256,:] ----------
__global__ void s1c_contrib(const float* __restrict__ pool, const void* __restrict__ Wx,
                            const int* __restrict__ flags, float* __restrict__ contrib){
  int s = blockIdx.x>>1;
  int cc = ((blockIdx.x&1)<<8) + threadIdx.x;
  bool bf = flags[0]!=0;
  const float* pl = pool + s*128;
  float acc=0.f;
  for(int k=0;k<128;k++) acc += pl[k]*ldf(Wx,(128+k)*512+cc,bf);
  contrib[s*512+cc]=acc;
}

// ---------- per-step: MFMA gates GEMM (M=64, N=512, K=192) + fused LSTM pointwise ----------
// 4 waves; wave w owns dims [w*32, w*32+32) of ALL FOUR gates -> LSTM pointwise is thread-local.
// No LDS, no barriers: A-frags and B-frags are direct 16B global loads in MFMA layout.
__launch_bounds__(256,2)
__global__ void s2_mfma(short* __restrict__ Apk, float* __restrict__ c_st,
                        const short* __restrict__ wT, const float* __restrict__ bias,
                        const float* __restrict__ contrib,
                        const void* __restrict__ segids, const int* __restrict__ flags,
                        const unsigned char* __restrict__ mask){
  const int tid = threadIdx.x;
  const int w   = tid>>6;
  const int l   = tid&63;
  const int lm  = l&15;
  const int lq  = l>>4;
  const int P0  = blockIdx.x*64;
  const bool i64 = flags[1]!=0;

  float4v acc[4][4][2];
  #pragma unroll
  for(int mt=0;mt<4;mt++)
    #pragma unroll
    for(int g=0;g<4;g++)
      #pragma unroll
      for(int j=0;j<2;j++) acc[mt][g][j] = (float4v)(0.f);

  const short* ap = Apk + (long long)(P0+lm)*KP + lq*8;
  const short* bp[4][2];
  #pragma unroll
  for(int g=0;g<4;g++)
    #pragma unroll
    for(int j=0;j<2;j++)
      bp[g][j] = wT + (long long)(g*128 + w*32 + j*16 + lm)*KP + lq*8;

  #pragma unroll
  for(int kc=0;kc<6;kc++){
    short8 a0 = *(const short8*)(ap + 0*16*KP + kc*32);
    short8 a1 = *(const short8*)(ap + 1*16*KP + kc*32);
    short8 a2 = *(const short8*)(ap + 2*16*KP + kc*32);
    short8 a3 = *(const short8*)(ap + 3*16*KP + kc*32);
    short8 b[4][2];
    #pragma unroll
    for(int g=0;g<4;g++)
      #pragma unroll
      for(int j=0;j<2;j++)
        b[g][j] = *(const short8*)(bp[g][j] + kc*32);
    #pragma unroll
    for(int g=0;g<4;g++)
      #pragma unroll
      for(int j=0;j<2;j++){
        acc[0][g][j] = __builtin_amdgcn_mfma_f32_16x16x32_bf16(a0, b[g][j], acc[0][g][j],0,0,0);
        acc[1][g][j] = __builtin_amdgcn_mfma_f32_16x16x32_bf16(a1, b[g][j], acc[1][g][j],0,0,0);
        acc[2][g][j] = __builtin_amdgcn_mfma_f32_16x16x32_bf16(a2, b[g][j], acc[2][g][j],0,0,0);
        acc[3][g][j] = __builtin_amdgcn_mfma_f32_16x16x32_bf16(a3, b[g][j], acc[3][g][j],0,0,0);
      }
  }

  float bi[4][2];
  #pragma unroll
  for(int g=0;g<4;g++)
    #pragma unroll
    for(int j=0;j<2;j++)
      bi[g][j] = bias[g*128 + w*32 + j*16 + lm];

  #pragma unroll
  for(int mt=0;mt<4;mt++){
    #pragma unroll
    for(int q=0;q<4;q++){
      int p = P0 + mt*16 + lq*4 + q;
      if(!mask[p]) continue;              // h2/c2 = old values: skip write entirely
      int sg = ldseg(segids,p,i64);
      const float* cb = contrib + (long long)sg*512;
      float* crow = c_st + (long long)p*128;
      bf16* hrow = (bf16*)Apk + (long long)p*KP + 42;
      #pragma unroll
      for(int j=0;j<2;j++){
        int d = w*32 + j*16 + lm;
        float gi = acc[mt][0][j][q] + bi[0][j] + cb[      d];
        float gf = acc[mt][1][j][q] + bi[1][j] + cb[128 + d];
        float gg = acc[mt][2][j][q] + bi[2][j] + cb[256 + d];
        float go = acc[mt][3][j][q] + bi[3][j] + cb[384 + d];
        float co = crow[d];
        float cn = sigm(gf)*co + sigm(gi)*tanh_f(gg);
        float hn = sigm(go)*tanh_f(cn);
        crow[d] = cn;
        hrow[d] = __float2bfloat16(hn);
      }
    }
  }
}

// ---------- per-step epilogue: out head, rel/pos, alpha softmax, fields->dtp, traj ----------
__global__ void s3_post(const short* __restrict__ Apk_c, short* __restrict__ Apk,
                        float* __restrict__ rel, float* __restrict__ pos, float* __restrict__ al,
                        const void* __restrict__ Wout, const void* __restrict__ bout,
                        const void* __restrict__ fieldA, const void* __restrict__ trans,
                        const int* __restrict__ flags,
                        const unsigned char* __restrict__ mask, void* __restrict__ traj, int t){
  int grp = threadIdx.x>>6, lane = threadIdx.x&63;
  int p = blockIdx.x*4+grp;
  bool bf = flags[0]!=0;
  const bf16* hrow = (const bf16*)Apk_c + (long long)p*KP + 42;
  float h0 = b2f(hrow[lane]), h1 = b2f(hrow[64+lane]);
  float o0 = h0*ldf(Wout,lane*2,bf)   + h1*ldf(Wout,(64+lane)*2,bf);
  float o1 = h0*ldf(Wout,lane*2+1,bf) + h1*ldf(Wout,(64+lane)*2+1,bf);
  for(int m=1;m<64;m<<=1){ o0 += __shfl_xor(o0,m); o1 += __shfl_xor(o1,m); }
  o0 += ldf(bout,0,bf); o1 += ldf(bout,1,bf);
  bool msk = mask[p]!=0;
  float r0 = rel[p*2], r1 = rel[p*2+1];
  if(msk){ r0=o0; r1=o1; }
  float pn0 = pos[p*2]+r0, pn1 = pos[p*2+1]+r1;
  float ad = -INFINITY;
  if(lane<NKK){
    float a2=0.f;
    for(int i=0;i<NKK;i++) a2 += al[(long long)p*NKK+i]*ldf(trans,i*NKK+lane,bf);
    ad = a2;
  }
  float mx = ad;
  for(int m=1;m<64;m<<=1) mx = fmaxf(mx, __shfl_xor(mx,m));
  float e = (lane<NKK)? __expf(ad-mx) : 0.f;
  float se = e;
  for(int m=1;m<64;m<<=1) se += __shfl_xor(se,m);
  float alp = e/se;
  if(msk && lane<NKK) al[(long long)p*NKK+lane] = alp;
  float alq = __shfl(alp, lane>>1);
  if(msk && lane<2*NKK){
    int kk=lane>>1, ee=lane&1;
    float fp = pn0*ldf(fieldA,kk*4+ee,bf) + pn1*ldf(fieldA,kk*4+2+ee,bf);
    ((bf16*)Apk)[(long long)p*KP+2+lane] = __float2bfloat16(fp*alq);
  }
  if(lane==0){
    if(msk){
      ((bf16*)Apk)[(long long)p*KP+0] = __float2bfloat16(r0);
      ((bf16*)Apk)[(long long)p*KP+1] = __float2bfloat16(r1);
    }
    rel[p*2]=r0; rel[p*2+1]=r1;
    pos[p*2]=pn0; pos[p*2+1]=pn1;
    long long base = (long long)t*N_PTS*2 + (long long)p*2;
    stf(traj, base,   r0, bf);
    stf(traj, base+1, r1, bf);
  }
}

extern "C" void kernel_launch(void* const* d_in, const int* in_sizes, int n_in,
                              void* d_out, int out_size, void* d_ws, size_t ws_size,
                              hipStream_t stream){
  const void* sf      = d_in[0];
  const void* lastpos = d_in[1];
  const void* alpha0  = d_in[2];
  const void* fd0     = d_in[3];
  const void* Wpos    = d_in[4];
  const void* bpos    = d_in[5];
  const void* Wfld    = d_in[6];
  const void* bfld    = d_in[7];
  const void* Wpool   = d_in[8];
  const void* bpool   = d_in[9];
  const void* Wx      = d_in[10];
  const void* Wh      = d_in[11];
  const void* blstm   = d_in[12];
  const void* Wout    = d_in[13];
  const void* bout    = d_in[14];
  const void* fieldA  = d_in[15];
  const void* trans   = d_in[16];
  const void* segids  = d_in[17];
  const unsigned char* maskraw = (const unsigned char*)d_in[18];

  char* ws = (char*)d_ws;
  size_t o = 0;
  auto alc = [&](size_t b){ size_t r=o; o=(o+b+255)&~(size_t)255; return r; };
  short* Apk     = (short*)(ws+alc((size_t)N_PTS*KP*2));
  float* c_st    = (float*)(ws+alc((size_t)N_PTS*128*4));
  float* rel     = (float*)(ws+alc((size_t)N_PTS*2*4));
  float* pos     = (float*)(ws+alc((size_t)N_PTS*2*4));
  float* al      = (float*)(ws+alc((size_t)N_PTS*20*4));
  int*   segst   = (int*)  (ws+alc((size_t)(NSEG+1)*4));
  float* segmax  = (float*)(ws+alc((size_t)NSEG*128*4));
  float* pool    = (float*)(ws+alc((size_t)NSEG*128*4));
  float* contrib = (float*)(ws+alc((size_t)NSEG*512*4));
  short* wT      = (short*)(ws+alc((size_t)512*KP*2));
  float* bias    = (float*)(ws+alc((size_t)512*4));
  unsigned char* mask = (unsigned char*)(ws+alc((size_t)N_PTS));
  int*   flags   = (int*)  (ws+alc(64));

  k_probe<<<1,64,0,stream>>>((const unsigned short*)Wx, (const int*)segids, maskraw, flags);
  k_conv<<<512,256,0,stream>>>(maskraw, flags, mask);
  k_segstart<<<33,256,0,stream>>>(segids, flags, segst);
  k_fold<<<386,256,0,stream>>>(Wpos,bpos,Wfld,bfld,Wx,Wh,blstm,flags,wT,bias);
  k_init<<<32768,256,0,stream>>>(sf,lastpos,alpha0,fd0,Wout,bout,flags,Apk,c_st,rel,pos,al,d_out);

  for(int t=1;t<PRED;t++){
    s1a_segmax<<<NSEG,128,0,stream>>>(Apk, segst, segmax);
    s1b_pool<<<NSEG/2,256,0,stream>>>(segmax, Wpool, bpool, flags, pool);
    s1c_contrib<<<NSEG*2,256,0,stream>>>(pool, Wx, flags, contrib);
    s2_mfma<<<N_PTS/64,256,0,stream>>>(Apk, c_st, wT, bias, contrib, segids, flags, mask);
    s3_post<<<N_PTS/4,256,0,stream>>>(Apk, Apk, rel, pos, al, Wout, bout, fieldA, trans, flags, mask, d_out, t);
  }
}